// Round 1
// baseline (691.456 us; speedup 1.0000x reference)
//
#include <hip/hip_runtime.h>
#include <hip/hip_bf16.h>

// GraphSAGE 2-layer encoder, MI355X.
// Pipeline: CSR build (hist/scan/scatter) -> mean-agg (f32 accumulate) ->
// fused dual GEMM (bf16 MFMA 16x16x32, f32 acc, bias[+relu] epilogue) x2.

typedef short short8 __attribute__((ext_vector_type(8)));
typedef float floatx4 __attribute__((ext_vector_type(4)));

#define IN_C  128
#define HID_C 256
#define OUT_C 128

static __device__ __forceinline__ unsigned short f2b(float f) {
  union { float f; unsigned u; } v; v.f = f;
  unsigned r = v.u + 0x7fffu + ((v.u >> 16) & 1u);   // round-to-nearest-even
  return (unsigned short)(r >> 16);
}
static __device__ __forceinline__ float b2f(unsigned short h) {
  union { unsigned u; float f; } v; v.u = ((unsigned)h) << 16;
  return v.f;
}

// ---------------- CSR build ----------------

__global__ void k_hist(const int* __restrict__ ei, int E, int* __restrict__ deg) {
  int e = blockIdx.x * blockDim.x + threadIdx.x;
  if (e < E) atomicAdd(&deg[ei[E + e]], 1);
}

// single-workgroup exclusive scan (N=50000: 49 chunks of 1024, trivial time)
__global__ void k_scan(const int* __restrict__ deg, int* __restrict__ offs,
                       int* __restrict__ cursor, int n) {
  __shared__ int buf[1024];
  __shared__ int carry;
  int tid = threadIdx.x;
  if (tid == 0) carry = 0;
  __syncthreads();
  for (int base = 0; base < n; base += 1024) {
    int idx = base + tid;
    int v = (idx < n) ? deg[idx] : 0;
    buf[tid] = v;
    __syncthreads();
    for (int off = 1; off < 1024; off <<= 1) {
      int t = (tid >= off) ? buf[tid - off] : 0;
      __syncthreads();
      buf[tid] += t;
      __syncthreads();
    }
    int excl = buf[tid] - v;
    if (idx < n) { int o = carry + excl; offs[idx] = o; cursor[idx] = o; }
    __syncthreads();
    if (tid == 1023) carry += buf[1023];
    __syncthreads();
  }
  if (tid == 0) offs[n] = carry;
}

__global__ void k_scatter(const int* __restrict__ ei, int E,
                          int* __restrict__ cursor, int* __restrict__ srcs) {
  int e = blockIdx.x * blockDim.x + threadIdx.x;
  if (e < E) {
    int d = ei[E + e];
    int pos = atomicAdd(&cursor[d], 1);
    srcs[pos] = ei[e];
  }
}

// ---------------- conversions ----------------

__global__ void k_f32_to_bf16(const float* __restrict__ in,
                              unsigned short* __restrict__ out, int n) {
  int i = blockIdx.x * blockDim.x + threadIdx.x;
  int stride = gridDim.x * blockDim.x;
  for (; i < n; i += stride) out[i] = f2b(in[i]);
}

// ---------------- mean aggregation (one block per node) ----------------

__global__ void k_agg_f32(const float* __restrict__ X, const int* __restrict__ offs,
                          const int* __restrict__ srcs, unsigned short* __restrict__ out) {
  int i = blockIdx.x;
  int c = threadIdx.x;                      // blockDim.x == IN_C == 128
  int beg = offs[i], end = offs[i + 1];
  float s = 0.f;
  for (int j = beg; j < end; ++j) {
    int src = srcs[j];
    s += X[(size_t)src * IN_C + c];
  }
  int d = end - beg;
  float inv = 1.0f / (float)(d > 0 ? d : 1);
  out[(size_t)i * IN_C + c] = f2b(s * inv);
}

__global__ void k_agg_bf16(const unsigned short* __restrict__ H, const int* __restrict__ offs,
                           const int* __restrict__ srcs, unsigned short* __restrict__ out) {
  int i = blockIdx.x;
  int c = threadIdx.x;                      // blockDim.x == HID_C == 256
  int beg = offs[i], end = offs[i + 1];
  float s = 0.f;
  for (int j = beg; j < end; ++j) {
    int src = srcs[j];
    s += b2f(H[(size_t)src * HID_C + c]);
  }
  int d = end - beg;
  float inv = 1.0f / (float)(d > 0 ? d : 1);
  out[(size_t)i * HID_C + c] = f2b(s * inv);
}

// ---------------- fused dual GEMM ----------------
// out[m][n] = sum_k1 A1[m][k]*Wl[n][k] + sum_k2 A2[m][k]*Wr[n][k] + bias[n]
// MFMA 16x16x32 bf16. Verified layouts (learn_hip m89/m120):
//   A frag: A[m = lane&15][k = (lane>>4)*8 + j], j=0..7 (16B contiguous)
//   B frag: B[k = (lane>>4)*8 + j][n = lane&15]  == W[n][k..k+7] (16B contiguous)
//   D:      D[row = (lane>>4)*4 + r][col = lane&15]
// Block = 4 waves; wave w covers cols n0 = blockIdx.y*64 + w*16. M tiles on blockIdx.x.
__global__ void k_gemm_dual(const unsigned short* __restrict__ A1,
                            const unsigned short* __restrict__ A2, int K1, int K2,
                            const unsigned short* __restrict__ Wl,
                            const unsigned short* __restrict__ Wr,
                            const float* __restrict__ bias, int Nout,
                            float* __restrict__ outF, unsigned short* __restrict__ outB) {
  int lane = threadIdx.x & 63;
  int wave = threadIdx.x >> 6;
  int l15 = lane & 15, quad = lane >> 4;
  int m0 = blockIdx.x * 16;
  int n0 = blockIdx.y * 64 + wave * 16;
  floatx4 acc = {0.f, 0.f, 0.f, 0.f};
  int kTot = K1 + K2;
  for (int k0 = 0; k0 < kTot; k0 += 32) {
    const unsigned short* Ap;
    const unsigned short* Wp;
    int kb;
    if (k0 < K1) {
      Ap = A1 + (size_t)(m0 + l15) * K1;
      Wp = Wl + (size_t)(n0 + l15) * K1;
      kb = k0;
    } else {
      Ap = A2 + (size_t)(m0 + l15) * K2;
      Wp = Wr + (size_t)(n0 + l15) * K2;
      kb = k0 - K1;
    }
    int kk = kb + quad * 8;
    short8 a = *reinterpret_cast<const short8*>(Ap + kk);
    short8 b = *reinterpret_cast<const short8*>(Wp + kk);
    acc = __builtin_amdgcn_mfma_f32_16x16x32_bf16(a, b, acc, 0, 0, 0);
  }
  int n = n0 + l15;
  float bv = bias[n];
  if (outF) {
#pragma unroll
    for (int r = 0; r < 4; ++r) {
      int m = m0 + quad * 4 + r;
      outF[(size_t)m * Nout + n] = acc[r] + bv;
    }
  } else {
#pragma unroll
    for (int r = 0; r < 4; ++r) {
      int m = m0 + quad * 4 + r;
      float v = acc[r] + bv;
      v = fmaxf(v, 0.f);                     // ReLU (layer-1 path)
      outB[(size_t)m * Nout + n] = f2b(v);
    }
  }
}

// ---------------- launch ----------------

extern "C" void kernel_launch(void* const* d_in, const int* in_sizes, int n_in,
                              void* d_out, int out_size, void* d_ws, size_t ws_size,
                              hipStream_t stream) {
  const float* x   = (const float*)d_in[0];
  const int*   ei  = (const int*)d_in[1];     // [2,E] int32
  const float* W1l = (const float*)d_in[2];   // [256,128]
  const float* b1  = (const float*)d_in[3];   // [256]
  const float* W1r = (const float*)d_in[4];   // [256,128]
  const float* W2l = (const float*)d_in[5];   // [128,256]
  const float* b2  = (const float*)d_in[6];   // [128]
  const float* W2r = (const float*)d_in[7];   // [128,256]
  float* out = (float*)d_out;

  int N = in_sizes[0] / IN_C;                 // 50000
  int E = in_sizes[1] / 2;                    // 800000

  // workspace carve-up (~81 MB total)
  char* p = (char*)d_ws;
  auto alloc = [&](size_t bytes) -> void* {
    void* r = (void*)p;
    p += (bytes + 255) & ~(size_t)255;
    return r;
  };
  int* deg    = (int*)alloc((size_t)N * 4);
  int* offs   = (int*)alloc(((size_t)N + 1) * 4);
  int* cursor = (int*)alloc((size_t)N * 4);
  int* srcs   = (int*)alloc((size_t)E * 4);
  unsigned short* xb   = (unsigned short*)alloc((size_t)N * IN_C * 2);
  unsigned short* agg1 = (unsigned short*)alloc((size_t)N * IN_C * 2);
  unsigned short* hb   = (unsigned short*)alloc((size_t)N * HID_C * 2);
  unsigned short* agg2 = (unsigned short*)alloc((size_t)N * HID_C * 2);
  unsigned short* w1l  = (unsigned short*)alloc((size_t)HID_C * IN_C * 2);
  unsigned short* w1r  = (unsigned short*)alloc((size_t)HID_C * IN_C * 2);
  unsigned short* w2l  = (unsigned short*)alloc((size_t)OUT_C * HID_C * 2);
  unsigned short* w2r  = (unsigned short*)alloc((size_t)OUT_C * HID_C * 2);

  // CSR build
  hipMemsetAsync(deg, 0, (size_t)N * 4, stream);
  k_hist<<<(E + 255) / 256, 256, 0, stream>>>(ei, E, deg);
  k_scan<<<1, 1024, 0, stream>>>(deg, offs, cursor, N);
  k_scatter<<<(E + 255) / 256, 256, 0, stream>>>(ei, E, cursor, srcs);

  // bf16 casts (x + weights)
  k_f32_to_bf16<<<1024, 256, 0, stream>>>(x, xb, N * IN_C);
  k_f32_to_bf16<<<64, 256, 0, stream>>>(W1l, w1l, HID_C * IN_C);
  k_f32_to_bf16<<<64, 256, 0, stream>>>(W1r, w1r, HID_C * IN_C);
  k_f32_to_bf16<<<64, 256, 0, stream>>>(W2l, w2l, OUT_C * HID_C);
  k_f32_to_bf16<<<64, 256, 0, stream>>>(W2r, w2r, OUT_C * HID_C);

  // layer 1: agg(x) -> h = relu([agg|x] @ [W1l|W1r]^T + b1), h stored bf16
  k_agg_f32<<<N, IN_C, 0, stream>>>(x, offs, srcs, agg1);
  k_gemm_dual<<<dim3(N / 16, HID_C / 64), 256, 0, stream>>>(
      agg1, xb, IN_C, IN_C, w1l, w1r, b1, HID_C, nullptr, hb);

  // layer 2: agg(h) -> out = [agg|h] @ [W2l|W2r]^T + b2 (f32)
  k_agg_bf16<<<N, HID_C, 0, stream>>>(hb, offs, srcs, agg2);
  k_gemm_dual<<<dim3(N / 16, OUT_C / 64), 256, 0, stream>>>(
      agg2, hb, HID_C, HID_C, w2l, w2r, b2, OUT_C, out, nullptr);
}

// Round 2
// 429.245 us; speedup vs baseline: 1.6109x; 1.6109x over previous
//
#include <hip/hip_runtime.h>
#include <hip/hip_bf16.h>

// GraphSAGE 2-layer encoder, MI355X. Round 2.
// Key algebraic move: mean-agg commutes with the linear layer, so layer 2
// computes z = h@W2l^T FIRST (N x 128) and gathers 128-wide rows instead of
// 256-wide. Both gathers read bf16 (256 B/row). Wave-per-node agg, 64x64
// GEMM tiles, shuffle-based scan.

typedef short short8 __attribute__((ext_vector_type(8)));
typedef float floatx4 __attribute__((ext_vector_type(4)));

#define IN_C  128
#define HID_C 256
#define OUT_C 128

static __device__ __forceinline__ unsigned short f2b(float f) {
  union { float f; unsigned u; } v; v.f = f;
  unsigned r = v.u + 0x7fffu + ((v.u >> 16) & 1u);   // RNE
  return (unsigned short)(r >> 16);
}
static __device__ __forceinline__ float lo2f(unsigned u) {   // low bf16 of pair
  union { unsigned u; float f; } v; v.u = u << 16; return v.f;
}
static __device__ __forceinline__ float hi2f(unsigned u) {   // high bf16 of pair
  union { unsigned u; float f; } v; v.u = u & 0xffff0000u; return v.f;
}

// ---------------- CSR build ----------------

__global__ void k_hist(const int* __restrict__ ei, int E, int* __restrict__ deg) {
  int e = blockIdx.x * blockDim.x + threadIdx.x;
  if (e < E) atomicAdd(&deg[ei[E + e]], 1);
}

// single-block scan, shuffle-based (1024 thr = 16 waves)
__global__ void k_scan(const int* __restrict__ deg, int* __restrict__ offs,
                       int* __restrict__ cursor, int n) {
  __shared__ int wsum[16];
  __shared__ int carry_s;
  int tid = threadIdx.x, lane = tid & 63, wv = tid >> 6;
  if (tid == 0) carry_s = 0;
  __syncthreads();
  for (int base = 0; base < n; base += 1024) {
    int idx = base + tid;
    int v = (idx < n) ? deg[idx] : 0;
    int s = v;
#pragma unroll
    for (int off = 1; off < 64; off <<= 1) {
      int t = __shfl_up(s, off, 64);
      if (lane >= off) s += t;
    }
    if (lane == 63) wsum[wv] = s;
    __syncthreads();
    if (wv == 0 && lane < 16) {
      int t = wsum[lane];
#pragma unroll
      for (int off = 1; off < 16; off <<= 1) {
        int u = __shfl_up(t, off, 64);
        if (lane >= off) t += u;
      }
      wsum[lane] = t;   // inclusive scan of wave sums
    }
    __syncthreads();
    int woff = (wv == 0) ? 0 : wsum[wv - 1];
    int carry = carry_s;
    int excl = carry + woff + s - v;
    if (idx < n) { offs[idx] = excl; cursor[idx] = excl; }
    __syncthreads();
    if (tid == 0) carry_s = carry + wsum[15];
    __syncthreads();
  }
  if (tid == 0) offs[n] = carry_s;
}

__global__ void k_scatter(const int* __restrict__ ei, int E,
                          int* __restrict__ cursor, int* __restrict__ srcs) {
  int e = blockIdx.x * blockDim.x + threadIdx.x;
  if (e < E) {
    int d = ei[E + e];
    int pos = atomicAdd(&cursor[d], 1);
    srcs[pos] = ei[e];
  }
}

// ---------------- f32 -> bf16 cast (2 elems/thread) ----------------

__global__ void k_cast(const float* __restrict__ in, unsigned* __restrict__ out, int nPairs) {
  int i = blockIdx.x * blockDim.x + threadIdx.x;
  int stride = gridDim.x * blockDim.x;
  for (; i < nPairs; i += stride) {
    float2 v = reinterpret_cast<const float2*>(in)[i];
    out[i] = (unsigned)f2b(v.x) | ((unsigned)f2b(v.y) << 16);
  }
}

// ---------------- mean aggregation: wave per node, 128 bf16 cols ----------------
// lane covers cols {2*lane, 2*lane+1}; one 4B load per edge per lane.

__global__ void k_agg_store(const unsigned* __restrict__ Z,   // N x 64 uint (128 bf16)
                            const int* __restrict__ offs, const int* __restrict__ srcs,
                            unsigned* __restrict__ out, int N) {
  int node = blockIdx.x * (blockDim.x >> 6) + (threadIdx.x >> 6);
  if (node >= N) return;
  int lane = threadIdx.x & 63;
  int beg = offs[node], end = offs[node + 1];
  float s0 = 0.f, s1 = 0.f;
  int j = beg;
  for (; j + 4 <= end; j += 4) {
    int i0 = srcs[j], i1 = srcs[j + 1], i2 = srcs[j + 2], i3 = srcs[j + 3];
    unsigned p0 = Z[(size_t)i0 * 64 + lane];
    unsigned p1 = Z[(size_t)i1 * 64 + lane];
    unsigned p2 = Z[(size_t)i2 * 64 + lane];
    unsigned p3 = Z[(size_t)i3 * 64 + lane];
    s0 += lo2f(p0) + lo2f(p1) + lo2f(p2) + lo2f(p3);
    s1 += hi2f(p0) + hi2f(p1) + hi2f(p2) + hi2f(p3);
  }
  for (; j < end; ++j) {
    unsigned p = Z[(size_t)srcs[j] * 64 + lane];
    s0 += lo2f(p); s1 += hi2f(p);
  }
  int d = end - beg;
  float inv = 1.0f / (float)(d > 0 ? d : 1);
  out[(size_t)node * 64 + lane] = (unsigned)f2b(s0 * inv) | ((unsigned)f2b(s1 * inv) << 16);
}

__global__ void k_agg_addout(const unsigned* __restrict__ Z,  // N x 64 uint (128 bf16)
                             const int* __restrict__ offs, const int* __restrict__ srcs,
                             float* __restrict__ Out, int N) {
  int node = blockIdx.x * (blockDim.x >> 6) + (threadIdx.x >> 6);
  if (node >= N) return;
  int lane = threadIdx.x & 63;
  int beg = offs[node], end = offs[node + 1];
  float s0 = 0.f, s1 = 0.f;
  int j = beg;
  for (; j + 4 <= end; j += 4) {
    int i0 = srcs[j], i1 = srcs[j + 1], i2 = srcs[j + 2], i3 = srcs[j + 3];
    unsigned p0 = Z[(size_t)i0 * 64 + lane];
    unsigned p1 = Z[(size_t)i1 * 64 + lane];
    unsigned p2 = Z[(size_t)i2 * 64 + lane];
    unsigned p3 = Z[(size_t)i3 * 64 + lane];
    s0 += lo2f(p0) + lo2f(p1) + lo2f(p2) + lo2f(p3);
    s1 += hi2f(p0) + hi2f(p1) + hi2f(p2) + hi2f(p3);
  }
  for (; j < end; ++j) {
    unsigned p = Z[(size_t)srcs[j] * 64 + lane];
    s0 += lo2f(p); s1 += hi2f(p);
  }
  int d = end - beg;
  float inv = 1.0f / (float)(d > 0 ? d : 1);
  float2* op = reinterpret_cast<float2*>(Out + (size_t)node * 128 + lane * 2);
  float2 v = *op;
  v.x += s0 * inv; v.y += s1 * inv;
  *op = v;
}

// ---------------- GEMM layer 1 ----------------
// h[m][n] = relu( sum_k agg1[m][k]*W1l[n][k] + sum_k xb[m][k]*W1r[n][k] + b1[n] )
// block = 64 rows x 64 cols; wave w -> 16 cols; 4 m-subtiles per wave.
__global__ void k_gemm1(const unsigned short* __restrict__ A1,  // N x 128 bf16
                        const unsigned short* __restrict__ A2,  // N x 128 bf16
                        const unsigned short* __restrict__ Wl,  // 256 x 128 bf16
                        const unsigned short* __restrict__ Wr,  // 256 x 128 bf16
                        const float* __restrict__ bias,         // 256
                        unsigned short* __restrict__ H, int M) {
  int lane = threadIdx.x & 63, wave = threadIdx.x >> 6;
  int l15 = lane & 15, quad = lane >> 4;
  int mBase = blockIdx.x * 64;
  int n0 = blockIdx.y * 64 + wave * 16;
  floatx4 acc[4] = {};
  for (int k0 = 0; k0 < 256; k0 += 32) {
    bool first = k0 < 128;
    const unsigned short* W = first ? Wl : Wr;
    const unsigned short* A = first ? A1 : A2;
    int kk = (first ? k0 : k0 - 128) + quad * 8;
    short8 b = *reinterpret_cast<const short8*>(W + (size_t)(n0 + l15) * 128 + kk);
#pragma unroll
    for (int s = 0; s < 4; ++s) {
      int m = mBase + s * 16 + l15;
      m = m < M ? m : M - 1;
      short8 a = *reinterpret_cast<const short8*>(A + (size_t)m * 128 + kk);
      acc[s] = __builtin_amdgcn_mfma_f32_16x16x32_bf16(a, b, acc[s], 0, 0, 0);
    }
  }
  int n = n0 + l15;
  float bv = bias[n];
#pragma unroll
  for (int s = 0; s < 4; ++s) {
#pragma unroll
    for (int r = 0; r < 4; ++r) {
      int m = mBase + s * 16 + quad * 4 + r;
      if (m < M) {
        float v = fmaxf(acc[s][r] + bv, 0.f);
        H[(size_t)m * 256 + n] = f2b(v);
      }
    }
  }
}

// ---------------- GEMM layer 2 (dual output) ----------------
// blockIdx.y in [0,4): cols 0..127 -> z = h@W2l^T (bf16), cols 128..255 -> out = h@W2r^T + b2 (f32)
__global__ void k_gemm2(const unsigned short* __restrict__ H,   // N x 256 bf16
                        const unsigned short* __restrict__ Wl,  // 128 x 256 bf16
                        const unsigned short* __restrict__ Wr,  // 128 x 256 bf16
                        const float* __restrict__ bias,         // 128
                        unsigned short* __restrict__ Zb,        // N x 128 bf16
                        float* __restrict__ Out, int M) {       // N x 128 f32
  int lane = threadIdx.x & 63, wave = threadIdx.x >> 6;
  int l15 = lane & 15, quad = lane >> 4;
  int mBase = blockIdx.x * 64;
  int nc = blockIdx.y * 64 + wave * 16 + l15;          // 0..255 combined
  const unsigned short* Wrow = (nc < 128)
      ? (Wl + (size_t)nc * 256) : (Wr + (size_t)(nc - 128) * 256);
  floatx4 acc[4] = {};
  for (int k0 = 0; k0 < 256; k0 += 32) {
    int kk = k0 + quad * 8;
    short8 b = *reinterpret_cast<const short8*>(Wrow + kk);
#pragma unroll
    for (int s = 0; s < 4; ++s) {
      int m = mBase + s * 16 + l15;
      m = m < M ? m : M - 1;
      short8 a = *reinterpret_cast<const short8*>(H + (size_t)m * 256 + kk);
      acc[s] = __builtin_amdgcn_mfma_f32_16x16x32_bf16(a, b, acc[s], 0, 0, 0);
    }
  }
  if (blockIdx.y < 2) {   // z path (bf16, no bias)
#pragma unroll
    for (int s = 0; s < 4; ++s)
#pragma unroll
      for (int r = 0; r < 4; ++r) {
        int m = mBase + s * 16 + quad * 4 + r;
        if (m < M) Zb[(size_t)m * 128 + nc] = f2b(acc[s][r]);
      }
  } else {                // out path (f32 + bias)
    int n = nc - 128;
    float bv = bias[n];
#pragma unroll
    for (int s = 0; s < 4; ++s)
#pragma unroll
      for (int r = 0; r < 4; ++r) {
        int m = mBase + s * 16 + quad * 4 + r;
        if (m < M) Out[(size_t)m * 128 + n] = acc[s][r] + bv;
      }
  }
}

// ---------------- launch ----------------

extern "C" void kernel_launch(void* const* d_in, const int* in_sizes, int n_in,
                              void* d_out, int out_size, void* d_ws, size_t ws_size,
                              hipStream_t stream) {
  const float* x   = (const float*)d_in[0];
  const int*   ei  = (const int*)d_in[1];
  const float* W1l = (const float*)d_in[2];
  const float* b1  = (const float*)d_in[3];
  const float* W1r = (const float*)d_in[4];
  const float* W2l = (const float*)d_in[5];
  const float* b2  = (const float*)d_in[6];
  const float* W2r = (const float*)d_in[7];
  float* out = (float*)d_out;

  int N = in_sizes[0] / IN_C;   // 50000
  int E = in_sizes[1] / 2;      // 800000

  char* p = (char*)d_ws;
  auto alloc = [&](size_t bytes) -> void* {
    void* r = (void*)p;
    p += (bytes + 255) & ~(size_t)255;
    return r;
  };
  int* deg    = (int*)alloc((size_t)N * 4);
  int* offs   = (int*)alloc(((size_t)N + 1) * 4);
  int* cursor = (int*)alloc((size_t)N * 4);
  int* srcs   = (int*)alloc((size_t)E * 4);
  unsigned* xb   = (unsigned*)alloc((size_t)N * IN_C * 2);       // bf16 pairs
  unsigned* agg1 = (unsigned*)alloc((size_t)N * IN_C * 2);
  unsigned short* hb = (unsigned short*)alloc((size_t)N * HID_C * 2);
  unsigned short* zb = (unsigned short*)alloc((size_t)N * OUT_C * 2);
  unsigned* w1l = (unsigned*)alloc((size_t)HID_C * IN_C * 2);
  unsigned* w1r = (unsigned*)alloc((size_t)HID_C * IN_C * 2);
  unsigned* w2l = (unsigned*)alloc((size_t)OUT_C * HID_C * 2);
  unsigned* w2r = (unsigned*)alloc((size_t)OUT_C * HID_C * 2);

  // CSR build
  hipMemsetAsync(deg, 0, (size_t)N * 4, stream);
  k_hist<<<(E + 255) / 256, 256, 0, stream>>>(ei, E, deg);
  k_scan<<<1, 1024, 0, stream>>>(deg, offs, cursor, N);
  k_scatter<<<(E + 255) / 256, 256, 0, stream>>>(ei, E, cursor, srcs);

  // casts
  k_cast<<<768, 256, 0, stream>>>(x, xb, N * IN_C / 2);
  k_cast<<<32, 256, 0, stream>>>(W1l, w1l, HID_C * IN_C / 2);
  k_cast<<<32, 256, 0, stream>>>(W1r, w1r, HID_C * IN_C / 2);
  k_cast<<<32, 256, 0, stream>>>(W2l, w2l, OUT_C * HID_C / 2);
  k_cast<<<32, 256, 0, stream>>>(W2r, w2r, OUT_C * HID_C / 2);

  int aggGrid = (N + 3) / 4;          // 4 nodes (waves) per 256-thr block
  int mBlocks = (N + 63) / 64;

  // layer 1: agg1 = mean-gather(xb); h = relu([agg1|xb]@[W1l|W1r]^T + b1)
  k_agg_store<<<aggGrid, 256, 0, stream>>>(xb, offs, srcs, agg1, N);
  k_gemm1<<<dim3(mBlocks, 4), 256, 0, stream>>>(
      (const unsigned short*)agg1, (const unsigned short*)xb,
      (const unsigned short*)w1l, (const unsigned short*)w1r, b1, hb, N);

  // layer 2: z = h@W2l^T, out = h@W2r^T + b2; then out += mean-gather(z)
  k_gemm2<<<dim3(mBlocks, 4), 256, 0, stream>>>(
      hb, (const unsigned short*)w2l, (const unsigned short*)w2r, b2, zb, out, N);
  k_agg_addout<<<aggGrid, 256, 0, stream>>>((const unsigned*)zb, offs, srcs, out, N);
}